// Round 8
// baseline (12711.690 us; speedup 1.0000x reference)
//
#include <hip/hip_runtime.h>
#include <math.h>

// Problem constants (from reference)
constexpr int cH  = 256;   // H
constexpr int cS  = 64;    // S (GRU seq len / p-dim)
constexpr int cAN = 16;    // AN
constexpr int cD  = 8;     // D
constexpr int cT  = 32;    // T
constexpr int cN  = 64;    // N (batch)
constexpr int cHG = 770;   // 2 + 3*H
constexpr int cG3 = 2310;  // 3*HG
constexpr int cOW = 338;   // 1+AN+1+H+S output row width
constexpr int XLD = 800;   // padded X row stride (zero-filled 770..800)
constexpr int GLD = 832;   // per-gate padded stride for git/wpad rows
constexpr int MLD = 2496;  // 3*GLD: per-v stride in gitp
constexpr int PROW = 2560; // padded row count/stride for wpadG + GRU partials

// ---------------------------------------------------------------------------
// One-off: gitp[v][g*832+k] = emb[v] . w_ih[g*770+k,:] + b_ih[...]  (padded layout)
__global__ __launch_bounds__(256) void k_gitab(const float* __restrict__ emb,
                                               const float* __restrict__ w_ih,
                                               const float* __restrict__ b_ih,
                                               float* __restrict__ gitp) {
  int v = blockIdx.y;
  int j = blockIdx.x * 256 + threadIdx.x;
  __shared__ float es[cH];
  es[threadIdx.x] = emb[v * cH + threadIdx.x];
  __syncthreads();
  if (j < cG3) {
    float acc = b_ih[j];
    const float* wr = w_ih + (size_t)j * cH;
    #pragma unroll 8
    for (int h = 0; h < cH; ++h) acc += wr[h] * es[h];
    int g = j / cHG, kk = j - g * cHG;
    gitp[(size_t)v * MLD + g * GLD + kk] = acc;
  }
}

// One-off: wpadG padded weights + zero the mega-kernel barrier state.
__global__ __launch_bounds__(256) void k_wpad(const float* __restrict__ whh,
                                              float* __restrict__ wpadG,
                                              unsigned* __restrict__ bar) {
  int idx = blockIdx.x * 256 + threadIdx.x;
  if (idx < 16) bar[idx] = 0u;
  if (idx < PROW * XLD) {
    int row = idx / XLD, col = idx - row * XLD;
    int g = row / GLD, k = row - g * GLD;
    wpadG[idx] = (g < 3 && k < cHG && col < cHG)
                     ? whh[(size_t)(g * cHG + k) * cHG + col] : 0.f;
  }
}

// One-off: psip[a][h][o] = psi_w[o, h*AN + a]  (coalesced access in tail)
__global__ __launch_bounds__(256) void k_psiperm(const float* __restrict__ psi_w,
                                                 float* __restrict__ psip) {
  int idx = blockIdx.x * 256 + threadIdx.x;      // a*65536 + h*256 + o
  int a = idx >> 16, h = (idx >> 8) & 255, o = idx & 255;
  psip[idx] = psi_w[((size_t)o * cH + h) * cAN + a];
}

// ---------------------------------------------------------------------------
// GRU GEMM for step s (round-5, verified @4611).
__global__ __launch_bounds__(256) void k_gru_gemm(const float* __restrict__ wpadG,
                                                  const float* __restrict__ X,
                                                  float* __restrict__ part, int s) {
  int tid = threadIdx.x;
  int tile = blockIdx.x % 40;          // (g, kt); tile 39 -> dummy rows
  int ks   = blockIdx.x / 40;          // split-K slice
  int g = tile / 13, kt = tile - g * 13;
  int cbase = (ks <= 2) ? ks * 13 : 38;
  int ccnt  = (ks < 2) ? 13 : 12;
  int kbase = cbase * 16;
  int csz = ccnt * 16;

  __shared__ float Bst[208][68];
  __shared__ float As[2][16][68];

  const float* bsrc = wpadG + ((size_t)(g * GLD + kt * 64)) * XLD + kbase;
  for (int i = tid; i < 64 * 208; i += 256) {
    int jl = i / 208, k2l = i - jl * 208;
    if (k2l < csz) Bst[k2l][jl] = bsrc[(size_t)jl * XLD + k2l];
  }

  int tm = tid & 15, tj = tid >> 4;
  int lrow = tid >> 2, lcol = (tid & 3) * 4;
  __syncthreads();

  float acc[4][4] = {};
  const float* Xp = X + ((size_t)lrow * cS + (s - 1)) * XLD + kbase;
  float4 av = *(const float4*)(Xp + lcol);
  for (int c = 0; c < ccnt; ++c) {
    int buf = c & 1;
    As[buf][lcol + 0][lrow] = av.x;
    As[buf][lcol + 1][lrow] = av.y;
    As[buf][lcol + 2][lrow] = av.z;
    As[buf][lcol + 3][lrow] = av.w;
    __syncthreads();
    if (c + 1 < ccnt) av = *(const float4*)(Xp + (c + 1) * 16 + lcol);
    #pragma unroll
    for (int kk = 0; kk < 16; ++kk) {
      float4 a4 = *(const float4*)&As[buf][kk][tm * 4];
      float4 b4 = *(const float4*)&Bst[c * 16 + kk][tj * 4];
      acc[0][0] += a4.x * b4.x; acc[0][1] += a4.x * b4.y; acc[0][2] += a4.x * b4.z; acc[0][3] += a4.x * b4.w;
      acc[1][0] += a4.y * b4.x; acc[1][1] += a4.y * b4.y; acc[1][2] += a4.y * b4.z; acc[1][3] += a4.y * b4.w;
      acc[2][0] += a4.z * b4.x; acc[2][1] += a4.z * b4.y; acc[2][2] += a4.z * b4.z; acc[2][3] += a4.z * b4.w;
      acc[3][0] += a4.w * b4.x; acc[3][1] += a4.w * b4.y; acc[3][2] += a4.w * b4.z; acc[3][3] += a4.w * b4.w;
    }
    __syncthreads();
  }
  float* pw = part + (size_t)ks * (64 * PROW) + (size_t)(g * GLD + kt * 64);
  #pragma unroll
  for (int i = 0; i < 4; ++i) {
    *(float4*)(pw + (size_t)(tm * 4 + i) * PROW + tj * 4) =
        make_float4(acc[i][0], acc[i][1], acc[i][2], acc[i][3]);
  }
}

// ---------------------------------------------------------------------------
// GRU gate phase for step s (round-5, verified).
__global__ __launch_bounds__(256) void k_gru_gate(const float* __restrict__ part,
                                                  const float* __restrict__ bhh,
                                                  const float* __restrict__ gitp,
                                                  const int* __restrict__ subtasks,
                                                  float* __restrict__ X, int s) {
  int kq = blockIdx.x, m = blockIdx.y, tid = threadIdx.x;
  if (tid >= 200) return;
  int k = kq * 200 + tid;
  float* xrow = X + ((size_t)m * cS + s) * XLD;
  if (k >= cHG) { if (k < XLD) xrow[k] = 0.f; return; }
  float accr = 0.f, accz = 0.f, accn = 0.f;
  if (s > 0) {
    const float* pm = part + (size_t)m * PROW;
    #pragma unroll
    for (int q = 0; q < 4; ++q) {
      const float* pq = pm + (size_t)q * (64 * PROW);
      accr += pq[k];
      accz += pq[GLD + k];
      accn += pq[2 * GLD + k];
    }
  }
  int v = subtasks[m * cS + s];
  const float* git = gitp + (size_t)v * MLD;
  float rg = 1.f / (1.f + expf(-(git[k]           + accr + bhh[k])));
  float zg = 1.f / (1.f + expf(-(git[GLD + k]     + accz + bhh[cHG + k])));
  float ng = tanhf(git[2 * GLD + k] + rg * (accn + bhh[2 * cHG + k]));
  float hp = (s > 0) ? X[((size_t)m * cS + (s - 1)) * XLD + k] : 0.f;
  xrow[k] = (1.f - zg) * ng + zg * hp;
}

// ---------------------------------------------------------------------------
// p_init + ||Mp||,||Mm|| + psb = softmax(p), r = psb @ M for t=0 (round-5).
__global__ __launch_bounds__(256) void k_pinit(const float* __restrict__ hxs,
                                               const float* __restrict__ X,
                                               float* __restrict__ psb,
                                               float* __restrict__ r,
                                               float* __restrict__ nMp,
                                               float* __restrict__ nMm) {
  int n = blockIdx.x, tid = threadIdx.x;
  __shared__ int anynz;
  __shared__ float pss[cS];
  __shared__ float mx, sm;
  if (tid == 0) anynz = 0;
  __syncthreads();
  int nz = (hxs[n * cOW + tid] != 0.f) ? 1 : 0;
  if (tid + 256 < cOW) nz |= (hxs[n * cOW + tid + 256] != 0.f) ? 1 : 0;
  if (nz) anynz = 1;
  __syncthreads();
  bool newep = (anynz == 0);
  if (tid < cS) {
    const float* xr = X + ((size_t)n * cS + tid) * XLD;
    float p0 = xr[1];
    float pv = newep ? p0 : hxs[n * cOW + 1 + cAN + 1 + cH + tid];
    pss[tid] = pv;
    float sp = 0.f, smn = 0.f;
    for (int h = 0; h < cH; ++h) {
      float vp = xr[2 + 2 * cH + h]; sp += vp * vp;
      float vm = xr[2 + cH + h];     smn += vm * vm;
    }
    nMp[n * cS + tid] = sqrtf(sp);
    nMm[n * cS + tid] = sqrtf(smn);
  }
  __syncthreads();
  if (tid == 0) { float m = pss[0]; for (int i = 1; i < cS; ++i) m = fmaxf(m, pss[i]); mx = m; }
  __syncthreads();
  if (tid < cS) pss[tid] = expf(pss[tid] - mx);
  __syncthreads();
  if (tid == 0) { float s = 0.f; for (int i = 0; i < cS; ++i) s += pss[i]; sm = s; }
  __syncthreads();
  if (tid < cS) { pss[tid] /= sm; psb[n * cS + tid] = pss[tid]; }
  __syncthreads();
  float acc = 0.f;
  for (int s2 = 0; s2 < cS; ++s2)
    acc += pss[s2] * X[((size_t)n * cS + s2) * XLD + 2 + tid];
  r[n * cH + tid] = acc;
}

// ---------------------------------------------------------------------------
// Persistent t-loop mega-kernel: 256 blocks (1/CU, co-resident). Phases are
// byte-identical ports of round-5's verified front/gemmT/gemmT/lin/tail.
// Hierarchical device barrier: 8 sub-counters (32 arrivals each) -> root;
// only the root is spin-read. Monotonic generations, no resets.
struct FrontS { float rsQ[64][65][4]; float w0s[64][9]; };
struct GemmS  { float As[16][68]; float Bs[16][68]; };
struct TailS  {
  float ss[cH]; float es[cH];
  float lg[cAN], dp[cAN], nzv[cAN], prb[cAN];
  float red[256]; float ared[16][17]; float cred[2][4][64];
  float enorm_s; float pns[cS]; float mx2, sm2;
};
union MegaS { FrontS f; GemmS g; TailS t; };

__device__ __forceinline__ void gbar(unsigned* sub, unsigned* root, int b, int ph) {
  __syncthreads();
  if (threadIdx.x == 0) {
    __threadfence();
    unsigned v = __hip_atomic_fetch_add(&sub[b & 7], 1u, __ATOMIC_ACQ_REL,
                                        __HIP_MEMORY_SCOPE_AGENT) + 1u;
    if (v == (unsigned)(32 * (ph + 1)))
      __hip_atomic_fetch_add(root, 1u, __ATOMIC_ACQ_REL, __HIP_MEMORY_SCOPE_AGENT);
    while (__hip_atomic_load(root, __ATOMIC_ACQUIRE, __HIP_MEMORY_SCOPE_AGENT) <
           (unsigned)(8 * (ph + 1))) {
      __builtin_amdgcn_s_sleep(2);
    }
  }
  __syncthreads();
}

__global__ __launch_bounds__(256) void k_mega(
    const float* __restrict__ base, const float* __restrict__ inter,
    const float* __restrict__ cw0, const float* __restrict__ cb0,
    const float* __restrict__ convs_w, const float* __restrict__ convs_b,
    const float* __restrict__ lin_w, const float* __restrict__ lin_b,
    const float* __restrict__ actor_w, const float* __restrict__ actor_b,
    const float* __restrict__ critic_w, const float* __restrict__ critic_b,
    const float* __restrict__ psip, const float* __restrict__ psi_b,
    const int* __restrict__ actions, const float* __restrict__ X,
    const float* __restrict__ nMp, const float* __restrict__ nMm,
    float* __restrict__ psb, float* __restrict__ r,
    float* __restrict__ x1T, float* __restrict__ x2T, float* __restrict__ x3t,
    float* __restrict__ out, unsigned* __restrict__ bar) {
  __shared__ MegaS sm;
  int b = blockIdx.x, tid = threadIdx.x;
  unsigned* sub = bar;
  unsigned* root = bar + 8;
  float* part = x1T;                 // lin partials alias x1T (round-5 layout)
  int ph = 0;

  for (int t = 0; t < cT; ++t) {
    // ---- P1: front (o = b) ----
    {
      int o = b;
      #pragma unroll
      for (int it = 0; it < 16; ++it) {
        int flat4 = it * 256 + tid;
        int n = flat4 >> 6, hq = flat4 & 63;
        float4 v = *(const float4*)(r + n * cH + hq * 4);
        *(float4*)&sm.f.rsQ[hq][n][0] = v;
      }
      __syncthreads();
      {
        int dg = tid >> 6, n = tid & 63;
        int d0 = dg * 2;
        const float* cwo = cw0 + (size_t)o * (cD * cH);
        float acc0 = 0.f, acc1 = 0.f;
        #pragma unroll 4
        for (int hq = 0; hq < 64; ++hq) {
          float4 rv = *(const float4*)&sm.f.rsQ[hq][n][0];
          #pragma unroll
          for (int j = 0; j < 4; ++j) {
            float2 w = *(const float2*)(cwo + (hq * 4 + j) * 8 + d0);
            float rvj = ((const float*)&rv)[j];
            acc0 += w.x * rvj;
            acc1 += w.y * rvj;
          }
        }
        sm.f.w0s[n][d0]     = acc0;
        sm.f.w0s[n][d0 + 1] = acc1;
      }
      __syncthreads();
      {
        int q = tid >> 6, n = tid & 63;
        float w0[8];
        #pragma unroll
        for (int d = 0; d < 8; ++d) w0[d] = sm.f.w0s[n][d];
        float bias = cb0[o];
        const float4* b4 = (const float4*)(base + ((size_t)(t * cN + n) * cD) * 64);
        float* dst = x1T + (size_t)o * 4096 + n * 64 + q * 16;
        #pragma unroll
        for (int k = 0; k < 4; ++k) {
          float4 acc = make_float4(bias, bias, bias, bias);
          #pragma unroll
          for (int d = 0; d < 8; ++d) {
            float4 bv = b4[d * 16 + q * 4 + k];
            acc.x += w0[d] * bv.x; acc.y += w0[d] * bv.y;
            acc.z += w0[d] * bv.z; acc.w += w0[d] * bv.w;
          }
          acc.x = fmaxf(acc.x, 0.f); acc.y = fmaxf(acc.y, 0.f);
          acc.z = fmaxf(acc.z, 0.f); acc.w = fmaxf(acc.w, 0.f);
          *(float4*)(dst + k * 4) = acc;
        }
      }
    }
    gbar(sub, root, b, ph++);

    // ---- P2/P3: conv GEMMs (nb = b>>6, mb = b&63) ----
    for (int cv = 0; cv < 2; ++cv) {
      const float* AT  = (cv == 0) ? x1T : x2T;
      const float* W   = convs_w + cv * 65536;
      const float* bia = convs_b + cv * 256;
      int nb = b >> 6, mb = b & 63;
      int tm = tid & 15, tj = tid >> 4;
      float acc[4][4] = {{0.f}};
      int lrow = tid >> 2, lcol = (tid & 3) * 4;
      int kr = tid >> 4, mc4 = (tid & 15) * 4;
      for (int kc = 0; kc < cH; kc += 16) {
        float4 av = *(const float4*)(AT + (size_t)(kc + kr) * 4096 + mb * 64 + mc4);
        float4 wv = *(const float4*)(W + (size_t)(nb * 64 + lrow) * cH + kc + lcol);
        *(float4*)&sm.g.As[kr][mc4] = av;
        sm.g.Bs[lcol][lrow] = wv.x; sm.g.Bs[lcol + 1][lrow] = wv.y;
        sm.g.Bs[lcol + 2][lrow] = wv.z; sm.g.Bs[lcol + 3][lrow] = wv.w;
        __syncthreads();
        #pragma unroll
        for (int kk = 0; kk < 16; ++kk) {
          float4 a4 = *(const float4*)&sm.g.As[kk][tm * 4];
          float4 b4 = *(const float4*)&sm.g.Bs[kk][tj * 4];
          acc[0][0] += a4.x * b4.x; acc[0][1] += a4.x * b4.y; acc[0][2] += a4.x * b4.z; acc[0][3] += a4.x * b4.w;
          acc[1][0] += a4.y * b4.x; acc[1][1] += a4.y * b4.y; acc[1][2] += a4.y * b4.z; acc[1][3] += a4.y * b4.w;
          acc[2][0] += a4.z * b4.x; acc[2][1] += a4.z * b4.y; acc[2][2] += a4.z * b4.z; acc[2][3] += a4.z * b4.w;
          acc[3][0] += a4.w * b4.x; acc[3][1] += a4.w * b4.y; acc[3][2] += a4.w * b4.z; acc[3][3] += a4.w * b4.w;
        }
        __syncthreads();
      }
      if (cv == 0) {
        #pragma unroll
        for (int j = 0; j < 4; ++j) {
          int o = nb * 64 + tj * 4 + j;
          float bv = bia[o];
          float4 o4;
          o4.x = fmaxf(acc[0][j] + bv, 0.f);
          o4.y = fmaxf(acc[1][j] + bv, 0.f);
          o4.z = fmaxf(acc[2][j] + bv, 0.f);
          o4.w = fmaxf(acc[3][j] + bv, 0.f);
          *(float4*)(x2T + (size_t)o * 4096 + mb * 64 + tm * 4) = o4;
        }
      } else {
        #pragma unroll
        for (int j = 0; j < 4; ++j) {
          int o = nb * 64 + tj * 4 + j;
          float bv = bia[o];
          float4 o4;
          o4.x = fmaxf(acc[0][j] + bv, 0.f);
          o4.y = fmaxf(acc[1][j] + bv, 0.f);
          o4.z = fmaxf(acc[2][j] + bv, 0.f);
          o4.w = fmaxf(acc[3][j] + bv, 0.f);
          *(float4*)(x3t + (size_t)mb * (64 * cH) + (size_t)o * 64 + tm * 4) = o4;
        }
      }
      gbar(sub, root, b, ph++);
    }

    // ---- P4: lin split-K (nb = b>>6, kcb = b&63) ----
    {
      int nb = b >> 6, kcb = b & 63;
      int tm = tid & 15, tj = tid >> 4;
      float acc[4][4] = {{0.f}};
      int lrow = tid >> 2, lcol = (tid & 3) * 4;
      for (int kc = 0; kc < 256; kc += 16) {
        float4 av = *(const float4*)(x3t + (size_t)lrow * 16384 + kcb * 256 + kc + lcol);
        float4 wv = *(const float4*)(lin_w + (size_t)(nb * 64 + lrow) * 16384 + kcb * 256 + kc + lcol);
        sm.g.As[lcol][lrow] = av.x; sm.g.As[lcol + 1][lrow] = av.y;
        sm.g.As[lcol + 2][lrow] = av.z; sm.g.As[lcol + 3][lrow] = av.w;
        sm.g.Bs[lcol][lrow] = wv.x; sm.g.Bs[lcol + 1][lrow] = wv.y;
        sm.g.Bs[lcol + 2][lrow] = wv.z; sm.g.Bs[lcol + 3][lrow] = wv.w;
        __syncthreads();
        #pragma unroll
        for (int kk = 0; kk < 16; ++kk) {
          float4 a4 = *(const float4*)&sm.g.As[kk][tm * 4];
          float4 b4 = *(const float4*)&sm.g.Bs[kk][tj * 4];
          acc[0][0] += a4.x * b4.x; acc[0][1] += a4.x * b4.y; acc[0][2] += a4.x * b4.z; acc[0][3] += a4.x * b4.w;
          acc[1][0] += a4.y * b4.x; acc[1][1] += a4.y * b4.y; acc[1][2] += a4.y * b4.z; acc[1][3] += a4.y * b4.w;
          acc[2][0] += a4.z * b4.x; acc[2][1] += a4.z * b4.y; acc[2][2] += a4.z * b4.z; acc[2][3] += a4.z * b4.w;
          acc[3][0] += a4.w * b4.x; acc[3][1] += a4.w * b4.y; acc[3][2] += a4.w * b4.z; acc[3][3] += a4.w * b4.w;
        }
        __syncthreads();
      }
      #pragma unroll
      for (int i = 0; i < 4; ++i) {
        int n = tm * 4 + i;
        float4 o4 = make_float4(acc[i][0], acc[i][1], acc[i][2], acc[i][3]);
        *(float4*)(part + ((size_t)kcb * cN + n) * cH + nb * 64 + tj * 4) = o4;
      }
    }
    gbar(sub, root, b, ph++);

    // ---- P5: tail (blocks 0..63 only) ----
    if (b < cN) {
      int n = b;
      float* orow = out + ((size_t)t * cN + n) * cOW;
      float acc = lin_b[tid];
      for (int kc = 0; kc < 64; ++kc) acc += part[((size_t)kc * cN + n) * cH + tid];
      float sv = fmaxf(acc, 0.f);
      sm.t.ss[tid] = sv;
      orow[1 + cAN + 1 + tid] = sv;
      __syncthreads();
      {
        int a = tid & 15, hg = tid >> 4;
        float pa = 0.f;
        const float* wr = actor_w + a * cH + hg * 16;
        const float* sh = &sm.t.ss[hg * 16];
        #pragma unroll
        for (int hh2 = 0; hh2 < 16; ++hh2) pa += wr[hh2] * sh[hh2];
        sm.t.ared[a][hg] = pa;
      }
      __syncthreads();
      if (tid < cAN) {
        float a = actor_b[tid];
        #pragma unroll
        for (int i = 0; i < 16; ++i) a += sm.t.ared[tid][i];
        sm.t.lg[tid] = a;
      }
      __syncthreads();
      if (tid < cAN) {
        float m = sm.t.lg[0];
        for (int i = 1; i < cAN; ++i) m = fmaxf(m, sm.t.lg[i]);
        sm.t.dp[tid] = expf(sm.t.lg[tid] - m);
      }
      __syncthreads();
      if (tid < cAN) {
        float s = 0.f;
        for (int i = 0; i < cAN; ++i) s += sm.t.dp[i];
        float dprob = sm.t.dp[tid] / s;
        float nv = (tid < 5) ? 1.f : inter[((size_t)t * cN + n) * (cAN - 5) + (tid - 5)];
        sm.t.nzv[tid] = nv;
        sm.t.prb[tid] = dprob * nv;
      }
      __syncthreads();
      if (tid < cAN) {
        float sp = 0.f, sn = 0.f;
        for (int i = 0; i < cAN; ++i) { sp += sm.t.prb[i]; sn += sm.t.nzv[i]; }
        float deficit = 1.f - sp;
        float v2 = sm.t.prb[tid] + (sm.t.nzv[tid] / fmaxf(sn, 1e-12f)) * deficit;
        sm.t.prb[tid] = fminf(fmaxf(v2, 0.f), 1.f);
      }
      __syncthreads();
      if (tid < cAN) {
        float s = 0.f;
        for (int i = 0; i < cAN; ++i) s += sm.t.prb[i];
        orow[1 + tid] = sm.t.prb[tid] / fmaxf(s, 1e-12f);
      }
      int at = actions[t * cN + n];
      {
        float a = psi_b[tid];
        for (int h = 0; h < cH; ++h) a += psip[((size_t)at * cH + h) * cH + tid] * sm.t.ss[h];
        sm.t.es[tid] = a;
        sm.t.red[tid] = a * a;
      }
      __syncthreads();
      for (int st = 128; st > 0; st >>= 1) {
        if (tid < st) sm.t.red[tid] += sm.t.red[tid + st];
        __syncthreads();
      }
      if (tid == 0) sm.t.enorm_s = sqrtf(sm.t.red[0]);
      __syncthreads();
      float enorm = sm.t.enorm_s;
      sm.t.red[tid] = critic_w[tid] * sm.t.ss[tid];
      __syncthreads();
      for (int st = 128; st > 0; st >>= 1) {
        if (tid < st) sm.t.red[tid] += sm.t.red[tid + st];
        __syncthreads();
      }
      if (tid == 0) {
        orow[1 + cAN] = sm.t.red[0] + critic_b[0];
        orow[0] = (float)at;
      }
      {
        int s2 = tid & 63, hg = tid >> 6;
        const float* xr = X + ((size_t)n * cS + s2) * XLD;
        const float* xp = xr + 2 + 2 * cH + hg * 64;
        const float* xm = xr + 2 + cH + hg * 64;
        const float* ep = &sm.t.es[hg * 64];
        float dpp = 0.f, dmm = 0.f;
        #pragma unroll 8
        for (int h2 = 0; h2 < 64; ++h2) {
          float ev = ep[h2];
          dpp += ev * xp[h2];
          dmm += ev * xm[h2];
        }
        sm.t.cred[0][hg][s2] = dpp;
        sm.t.cred[1][hg][s2] = dmm;
      }
      __syncthreads();
      if (tid < cS) {
        float dpp = sm.t.cred[0][0][tid] + sm.t.cred[0][1][tid] + sm.t.cred[0][2][tid] + sm.t.cred[0][3][tid];
        float dmm = sm.t.cred[1][0][tid] + sm.t.cred[1][1][tid] + sm.t.cred[1][2][tid] + sm.t.cred[1][3][tid];
        const float* xr = X + ((size_t)n * cS + tid) * XLD;
        float cP = dpp / fmaxf(enorm * nMp[n * cS + tid], 1e-8f);
        float cM = dmm / fmaxf(enorm * nMm[n * cS + tid], 1e-8f);
        float cc = xr[0];
        float pn = psb[n * cS + tid] + cc * cP - cc * cM;
        sm.t.pns[tid] = pn;
        orow[1 + cAN + 1 + cH + tid] = pn;
      }
      __threadfence_block();
      __syncthreads();
      if (t == cT - 1) {
        float* orow2 = out + (size_t)cT * cN * cOW + (size_t)n * cOW;
        orow2[tid] = orow[tid];
        if (tid + 256 < cOW) orow2[tid + 256] = orow[tid + 256];
      }
      if (tid == 0) { float m2 = sm.t.pns[0]; for (int i = 1; i < cS; ++i) m2 = fmaxf(m2, sm.t.pns[i]); sm.t.mx2 = m2; }
      __syncthreads();
      if (tid < cS) sm.t.pns[tid] = expf(sm.t.pns[tid] - sm.t.mx2);
      __syncthreads();
      if (tid == 0) { float s2 = 0.f; for (int i = 0; i < cS; ++i) s2 += sm.t.pns[i]; sm.t.sm2 = s2; }
      __syncthreads();
      if (tid < cS) { sm.t.pns[tid] /= sm.t.sm2; psb[n * cS + tid] = sm.t.pns[tid]; }
      __syncthreads();
      float acc2 = 0.f;
      for (int s2 = 0; s2 < cS; ++s2)
        acc2 += sm.t.pns[s2] * X[((size_t)n * cS + s2) * XLD + 2 + tid];
      r[n * cH + tid] = acc2;
    }
    gbar(sub, root, b, ph++);
  }
}

// ---------------------------------------------------------------------------
extern "C" void kernel_launch(void* const* d_in, const int* in_sizes, int n_in,
                              void* d_out, int out_size, void* d_ws, size_t ws_size,
                              hipStream_t stream) {
  const float* base     = (const float*)d_in[0];
  const float* inter    = (const float*)d_in[1];
  const float* hxs      = (const float*)d_in[2];
  const float* emb      = (const float*)d_in[3];
  const float* w_ih     = (const float*)d_in[4];
  const float* w_hh     = (const float*)d_in[5];
  const float* b_ih     = (const float*)d_in[6];
  const float* b_hh     = (const float*)d_in[7];
  const float* conv0_w  = (const float*)d_in[8];
  const float* conv0_b  = (const float*)d_in[9];
  const float* convs_w  = (const float*)d_in[10];
  const float* convs_b  = (const float*)d_in[11];
  const float* lin_w    = (const float*)d_in[12];
  const float* lin_b    = (const float*)d_in[13];
  const float* psi_w    = (const float*)d_in[14];
  const float* psi_b    = (const float*)d_in[15];
  const float* actor_w  = (const float*)d_in[16];
  const float* actor_b  = (const float*)d_in[17];
  const float* critic_w = (const float*)d_in[18];
  const float* critic_b = (const float*)d_in[19];
  const int*   subtasks = (const int*)d_in[20];
  const int*   actions  = (const int*)d_in[21];
  float* out = (float*)d_out;
  float* ws  = (float*)d_ws;

  // ws layout (floats), round-5 + 16-float barrier region at the end.
  float* gitp   = ws + 0;          // 79,872  [GRU]
  float* psb    = ws + 0;          // 4,096   (post-GRU)
  float* r      = ws + 4096;       // 16,384
  float* nMp    = ws + 20480;      // 4,096
  float* nMm    = ws + 24576;      // 4,096
  float* X      = ws + 79872;      // 3,276,800 (persists)
  float* wpadG  = ws + 3356672;    // 2,048,000 [GRU]
  float* psip   = ws + 3356672;    // 1,048,576 (post-GRU)
  float* x1T    = ws + 4405248;    // 1,048,576 [t-loop] (aliased by lin partials)
  float* partG  = ws + 5404672;    // 655,360 [GRU]
  float* x2T    = ws + 5453824;    // 1,048,576 [t-loop] (overlaps partG: GRU-only)
  float* x3t    = ws + 6502400;    // 1,048,576 [t-loop]
  unsigned* bar = (unsigned*)(ws + 7550976);  // 16 u32 -> end 7,550,992

  k_gitab<<<dim3(10, 32), 256, 0, stream>>>(emb, w_ih, b_ih, gitp);
  k_wpad<<<8000, 256, 0, stream>>>(w_hh, wpadG, bar);
  k_gru_gate<<<dim3(4, 64), 256, 0, stream>>>(partG, b_hh, gitp, subtasks, X, 0);
  for (int s = 1; s < cS; ++s) {
    k_gru_gemm<<<160, 256, 0, stream>>>(wpadG, X, partG, s);
    k_gru_gate<<<dim3(4, 64), 256, 0, stream>>>(partG, b_hh, gitp, subtasks, X, s);
  }
  k_psiperm<<<4096, 256, 0, stream>>>(psi_w, psip);  // after GRU (psip aliases wpadG)
  k_pinit<<<64, 256, 0, stream>>>(hxs, X, psb, r, nMp, nMm);
  k_mega<<<256, 256, 0, stream>>>(base, inter, conv0_w, conv0_b, convs_w, convs_b,
                                  lin_w, lin_b, actor_w, actor_b, critic_w, critic_b,
                                  psip, psi_b, actions, X, nMp, nMm,
                                  psb, r, x1T, x2T, x3t, out, bar);
}

// Round 9
// 4431.399 us; speedup vs baseline: 2.8685x; 2.8685x over previous
//
#include <hip/hip_runtime.h>
#include <math.h>

// Problem constants (from reference)
constexpr int cH  = 256;   // H
constexpr int cS  = 64;    // S (GRU seq len / p-dim)
constexpr int cAN = 16;    // AN
constexpr int cD  = 8;     // D
constexpr int cT  = 32;    // T
constexpr int cN  = 64;    // N (batch)
constexpr int cHG = 770;   // 2 + 3*H
constexpr int cG3 = 2310;  // 3*HG
constexpr int cOW = 338;   // 1+AN+1+H+S output row width
constexpr int XLD = 800;   // padded X row stride (zero-filled 770..800)
constexpr int GLD = 832;   // per-gate padded stride for git/wpad rows
constexpr int MLD = 2496;  // 3*GLD: per-v stride in gitp
constexpr int PROW = 2560; // padded row count/stride for wpadG + GRU partials

// ---------------------------------------------------------------------------
// One-off: gitp[v][g*832+k] = emb[v] . w_ih[g*770+k,:] + b_ih[...]  (padded layout)
__global__ __launch_bounds__(256) void k_gitab(const float* __restrict__ emb,
                                               const float* __restrict__ w_ih,
                                               const float* __restrict__ b_ih,
                                               float* __restrict__ gitp) {
  int v = blockIdx.y;
  int j = blockIdx.x * 256 + threadIdx.x;
  __shared__ float es[cH];
  es[threadIdx.x] = emb[v * cH + threadIdx.x];
  __syncthreads();
  if (j < cG3) {
    float acc = b_ih[j];
    const float* wr = w_ih + (size_t)j * cH;
    #pragma unroll 8
    for (int h = 0; h < cH; ++h) acc += wr[h] * es[h];
    int g = j / cHG, kk = j - g * cHG;
    gitp[(size_t)v * MLD + g * GLD + kk] = acc;
  }
}

// One-off: wpadG[(g*832+k)][k2] = whh[g*770+k][k2], zero-padded rows/cols,
// extended to PROW=2560 rows (rows 2496.. are all-zero dummy-tile rows).
__global__ __launch_bounds__(256) void k_wpad(const float* __restrict__ whh,
                                              float* __restrict__ wpadG) {
  int idx = blockIdx.x * 256 + threadIdx.x;
  if (idx < PROW * XLD) {
    int row = idx / XLD, col = idx - row * XLD;
    int g = row / GLD, k = row - g * GLD;
    wpadG[idx] = (g < 3 && k < cHG && col < cHG)
                     ? whh[(size_t)(g * cHG + k) * cHG + col] : 0.f;
  }
}

// One-off: psip[a][h][o] = psi_w[o, h*AN + a]  (coalesced access in tail)
__global__ __launch_bounds__(256) void k_psiperm(const float* __restrict__ psi_w,
                                                 float* __restrict__ psip) {
  int idx = blockIdx.x * 256 + threadIdx.x;      // a*65536 + h*256 + o
  int a = idx >> 16, h = (idx >> 8) & 255, o = idx & 255;
  psip[idx] = psi_w[((size_t)o * cH + h) * cAN + a];
}

// ---------------------------------------------------------------------------
// GRU GEMM for step s (round-5, verified @4611).
// grid = 160 (40 tiles x 4 split-K; tile 39 is a zero dummy for grid%8==0).
__global__ __launch_bounds__(256) void k_gru_gemm(const float* __restrict__ wpadG,
                                                  const float* __restrict__ X,
                                                  float* __restrict__ part, int s) {
  int tid = threadIdx.x;
  int tile = blockIdx.x % 40;          // (g, kt); tile 39 -> dummy rows
  int ks   = blockIdx.x / 40;          // split-K slice
  int g = tile / 13, kt = tile - g * 13;
  int cbase = (ks <= 2) ? ks * 13 : 38;
  int ccnt  = (ks < 2) ? 13 : 12;
  int kbase = cbase * 16;
  int csz = ccnt * 16;

  __shared__ float Bst[208][68];       // B^T slice: [k2_local][j_local]
  __shared__ float As[2][16][68];      // A^T staging double buffer

  const float* bsrc = wpadG + ((size_t)(g * GLD + kt * 64)) * XLD + kbase;
  for (int i = tid; i < 64 * 208; i += 256) {
    int jl = i / 208, k2l = i - jl * 208;
    if (k2l < csz) Bst[k2l][jl] = bsrc[(size_t)jl * XLD + k2l];
  }

  int tm = tid & 15, tj = tid >> 4;
  int lrow = tid >> 2, lcol = (tid & 3) * 4;
  __syncthreads();

  float acc[4][4] = {};
  const float* Xp = X + ((size_t)lrow * cS + (s - 1)) * XLD + kbase;
  float4 av = *(const float4*)(Xp + lcol);
  for (int c = 0; c < ccnt; ++c) {
    int buf = c & 1;
    As[buf][lcol + 0][lrow] = av.x;
    As[buf][lcol + 1][lrow] = av.y;
    As[buf][lcol + 2][lrow] = av.z;
    As[buf][lcol + 3][lrow] = av.w;
    __syncthreads();
    if (c + 1 < ccnt) av = *(const float4*)(Xp + (c + 1) * 16 + lcol);
    #pragma unroll
    for (int kk = 0; kk < 16; ++kk) {
      float4 a4 = *(const float4*)&As[buf][kk][tm * 4];
      float4 b4 = *(const float4*)&Bst[c * 16 + kk][tj * 4];
      acc[0][0] += a4.x * b4.x; acc[0][1] += a4.x * b4.y; acc[0][2] += a4.x * b4.z; acc[0][3] += a4.x * b4.w;
      acc[1][0] += a4.y * b4.x; acc[1][1] += a4.y * b4.y; acc[1][2] += a4.y * b4.z; acc[1][3] += a4.y * b4.w;
      acc[2][0] += a4.z * b4.x; acc[2][1] += a4.z * b4.y; acc[2][2] += a4.z * b4.z; acc[2][3] += a4.z * b4.w;
      acc[3][0] += a4.w * b4.x; acc[3][1] += a4.w * b4.y; acc[3][2] += a4.w * b4.z; acc[3][3] += a4.w * b4.w;
    }
    __syncthreads();
  }
  float* pw = part + (size_t)ks * (64 * PROW) + (size_t)(g * GLD + kt * 64);
  #pragma unroll
  for (int i = 0; i < 4; ++i) {
    *(float4*)(pw + (size_t)(tm * 4 + i) * PROW + tj * 4) =
        make_float4(acc[i][0], acc[i][1], acc[i][2], acc[i][3]);
  }
}

// ---------------------------------------------------------------------------
// GRU gate phase for step s (round-5, verified).
__global__ __launch_bounds__(256) void k_gru_gate(const float* __restrict__ part,
                                                  const float* __restrict__ bhh,
                                                  const float* __restrict__ gitp,
                                                  const int* __restrict__ subtasks,
                                                  float* __restrict__ X, int s) {
  int kq = blockIdx.x, m = blockIdx.y, tid = threadIdx.x;
  if (tid >= 200) return;
  int k = kq * 200 + tid;
  float* xrow = X + ((size_t)m * cS + s) * XLD;
  if (k >= cHG) { if (k < XLD) xrow[k] = 0.f; return; }
  float accr = 0.f, accz = 0.f, accn = 0.f;
  if (s > 0) {
    const float* pm = part + (size_t)m * PROW;
    #pragma unroll
    for (int q = 0; q < 4; ++q) {
      const float* pq = pm + (size_t)q * (64 * PROW);
      accr += pq[k];
      accz += pq[GLD + k];
      accn += pq[2 * GLD + k];
    }
  }
  int v = subtasks[m * cS + s];
  const float* git = gitp + (size_t)v * MLD;
  float rg = 1.f / (1.f + expf(-(git[k]           + accr + bhh[k])));
  float zg = 1.f / (1.f + expf(-(git[GLD + k]     + accz + bhh[cHG + k])));
  float ng = tanhf(git[2 * GLD + k] + rg * (accn + bhh[2 * cHG + k]));
  float hp = (s > 0) ? X[((size_t)m * cS + (s - 1)) * XLD + k] : 0.f;
  xrow[k] = (1.f - zg) * ng + zg * hp;
}

// ---------------------------------------------------------------------------
// p_init + ||Mp||,||Mm|| + psb = softmax(p), r = psb @ M for t=0 (round-5).
__global__ __launch_bounds__(256) void k_pinit(const float* __restrict__ hxs,
                                               const float* __restrict__ X,
                                               float* __restrict__ psb,
                                               float* __restrict__ r,
                                               float* __restrict__ nMp,
                                               float* __restrict__ nMm) {
  int n = blockIdx.x, tid = threadIdx.x;
  __shared__ int anynz;
  __shared__ float pss[cS];
  __shared__ float mx, sm;
  if (tid == 0) anynz = 0;
  __syncthreads();
  int nz = (hxs[n * cOW + tid] != 0.f) ? 1 : 0;
  if (tid + 256 < cOW) nz |= (hxs[n * cOW + tid + 256] != 0.f) ? 1 : 0;
  if (nz) anynz = 1;
  __syncthreads();
  bool newep = (anynz == 0);
  if (tid < cS) {
    const float* xr = X + ((size_t)n * cS + tid) * XLD;
    float p0 = xr[1];
    float pv = newep ? p0 : hxs[n * cOW + 1 + cAN + 1 + cH + tid];
    pss[tid] = pv;
    float sp = 0.f, smn = 0.f;
    for (int h = 0; h < cH; ++h) {
      float vp = xr[2 + 2 * cH + h]; sp += vp * vp;
      float vm = xr[2 + cH + h];     smn += vm * vm;
    }
    nMp[n * cS + tid] = sqrtf(sp);
    nMm[n * cS + tid] = sqrtf(smn);
  }
  __syncthreads();
  if (tid == 0) { float m = pss[0]; for (int i = 1; i < cS; ++i) m = fmaxf(m, pss[i]); mx = m; }
  __syncthreads();
  if (tid < cS) pss[tid] = expf(pss[tid] - mx);
  __syncthreads();
  if (tid == 0) { float s = 0.f; for (int i = 0; i < cS; ++i) s += pss[i]; sm = s; }
  __syncthreads();
  if (tid < cS) { pss[tid] /= sm; psb[n * cS + tid] = pss[tid]; }
  __syncthreads();
  float acc = 0.f;
  for (int s2 = 0; s2 < cS; ++s2)
    acc += pss[s2] * X[((size_t)n * cS + s2) * XLD + 2 + tid];
  r[n * cH + tid] = acc;
}

// ---------------------------------------------------------------------------
// Front Phase A only: W0r[n][o][d] = sum_h conv0_w[o][h*8+d] * r[n][h].
// Block = one output channel o (grid 256): per-o weight decomposition —
// each block reads a distinct 8KB weight slice (no duplication).
__global__ __launch_bounds__(256) void k_front0(const float* __restrict__ r,
                                                const float* __restrict__ cw,
                                                float* __restrict__ w0r) {
  int o = blockIdx.x, tid = threadIdx.x;
  __shared__ float rsQ[64][65][4];   // [hq][n][j]: r[n][hq*4+j], padded rows
  #pragma unroll
  for (int it = 0; it < 16; ++it) {
    int flat4 = it * 256 + tid;          // (n,hq) pair index
    int n = flat4 >> 6, hq = flat4 & 63;
    float4 v = *(const float4*)(r + n * cH + hq * 4);
    *(float4*)&rsQ[hq][n][0] = v;
  }
  __syncthreads();
  // wave w handles d0 = 2w, d0+1; lane n = tid&63 (identical to round-5 front)
  int dg = tid >> 6, n = tid & 63;
  int d0 = dg * 2;
  const float* cwo = cw + (size_t)o * (cD * cH);   // [h*8+d]
  float acc0 = 0.f, acc1 = 0.f;
  #pragma unroll 4
  for (int hq = 0; hq < 64; ++hq) {
    float4 rv = *(const float4*)&rsQ[hq][n][0];
    #pragma unroll
    for (int j = 0; j < 4; ++j) {
      float2 w = *(const float2*)(cwo + (hq * 4 + j) * 8 + d0);
      float rvj = ((const float*)&rv)[j];
      acc0 += w.x * rvj;
      acc1 += w.y * rvj;
    }
  }
  w0r[(size_t)n * 2048 + o * 8 + d0]     = acc0;
  w0r[(size_t)n * 2048 + o * 8 + d0 + 1] = acc1;
}

// ---------------------------------------------------------------------------
// Fused front-Phase-B + conv1 per (nb, n): x1 tile recomputed in LDS (never
// materialized in global), then conv1 GEMM. Grid 256 1-D, XCD-co-located:
// b = (n%8) | 8*nb | 32*(n>>3) -> all 4 nb-dups of n share an XCD.
// (round-6 verbatim; correctness-verified there.)
__global__ __launch_bounds__(256) void k_conv1f(const float* __restrict__ w0r,
                                                const float* __restrict__ base,
                                                const float* __restrict__ cb0,
                                                const float* __restrict__ W1,
                                                const float* __restrict__ b1,
                                                float* __restrict__ y1T, int t) {
  int b = blockIdx.x, tid = threadIdx.x;
  int n  = (b & 7) | ((b >> 5) << 3);
  int nb = (b >> 3) & 3;
  __shared__ float x1s[256][68];   // [o][ij] A^T tile (aligned float4 rows)
  __shared__ float w0s[256][9];    // [o][d] + bias in [8]
  __shared__ float bs[8][64];      // base[n][d][ij]
  __shared__ float Bs[16][68];
  // stage W0r[n] + cb0 + base[n]
  {
    const float* src = w0r + (size_t)n * 2048 + tid * 8;
    float4 va = *(const float4*)(src);
    float4 vb = *(const float4*)(src + 4);
    *(float4*)&w0s[tid][0] = va;
    *(float4*)&w0s[tid][4] = vb;
    w0s[tid][8] = cb0[tid];
  }
  if (tid < 128) {
    int d = tid >> 4, c4 = (tid & 15) * 4;
    *(float4*)&bs[d][c4] =
        *(const float4*)(base + ((size_t)(t * cN + n) * cD + d) * 64 + c4);
  }
  __syncthreads();
  // Phase B: x1s[o][ij] = relu(b0[o] + sum_d W0r*base); lane = ij (bank-clean)
  {
    int wv = tid >> 6, ln = tid & 63;
    for (int oi = 0; oi < 64; ++oi) {
      int o = wv * 64 + oi;
      float acc = w0s[o][8];
      #pragma unroll
      for (int d = 0; d < 8; ++d) acc += w0s[o][d] * bs[d][ln];
      x1s[o][ln] = fmaxf(acc, 0.f);
    }
  }
  __syncthreads();
  // conv1 GEMM: y1 = relu(x1 @ W1^T + b1) -> y1T[o][n*64+ij]
  int tm = tid & 15, tj = tid >> 4;
  int lrow = tid >> 2, lcol = (tid & 3) * 4;
  float acc[4][4] = {{0.f}};
  for (int kc = 0; kc < cH; kc += 16) {
    float4 wv4 = *(const float4*)(W1 + (size_t)(nb * 64 + lrow) * cH + kc + lcol);
    Bs[lcol][lrow] = wv4.x; Bs[lcol + 1][lrow] = wv4.y;
    Bs[lcol + 2][lrow] = wv4.z; Bs[lcol + 3][lrow] = wv4.w;
    __syncthreads();
    #pragma unroll
    for (int kk = 0; kk < 16; ++kk) {
      float4 a4 = *(const float4*)&x1s[kc + kk][tm * 4];
      float4 b4 = *(const float4*)&Bs[kk][tj * 4];
      acc[0][0] += a4.x * b4.x; acc[0][1] += a4.x * b4.y; acc[0][2] += a4.x * b4.z; acc[0][3] += a4.x * b4.w;
      acc[1][0] += a4.y * b4.x; acc[1][1] += a4.y * b4.y; acc[1][2] += a4.y * b4.z; acc[1][3] += a4.y * b4.w;
      acc[2][0] += a4.z * b4.x; acc[2][1] += a4.z * b4.y; acc[2][2] += a4.z * b4.z; acc[2][3] += a4.z * b4.w;
      acc[3][0] += a4.w * b4.x; acc[3][1] += a4.w * b4.y; acc[3][2] += a4.w * b4.z; acc[3][3] += a4.w * b4.w;
    }
    __syncthreads();
  }
  #pragma unroll
  for (int j = 0; j < 4; ++j) {
    int o = nb * 64 + tj * 4 + j;
    float bv = b1[o];
    float4 o4;
    o4.x = fmaxf(acc[0][j] + bv, 0.f);
    o4.y = fmaxf(acc[1][j] + bv, 0.f);
    o4.z = fmaxf(acc[2][j] + bv, 0.f);
    o4.w = fmaxf(acc[3][j] + bv, 0.f);
    *(float4*)(y1T + (size_t)o * 4096 + n * 64 + tm * 4) = o4;
  }
}

// ---------------------------------------------------------------------------
// 1x1 conv GEMM, transposed-activation flavor (round-5). A^T in: AT[256][4096].
// mode 0: write CT[o][m];  mode 1: write x3t[n, o*64+ij]
__global__ __launch_bounds__(256) void k_gemmT(const float* __restrict__ AT,
                                               const float* __restrict__ W,
                                               const float* __restrict__ bias,
                                               float* __restrict__ C, int mode) {
  int nb = blockIdx.x, mb = blockIdx.y, tid = threadIdx.x;
  int tm = tid & 15, tj = tid >> 4;
  __shared__ float As[16][68];
  __shared__ float Bs[16][68];
  float acc[4][4] = {{0.f}};
  int lrow = tid >> 2, lcol = (tid & 3) * 4;   // B staging coords
  int kr = tid >> 4, mc4 = (tid & 15) * 4;     // A staging coords (direct)
  for (int kc = 0; kc < cH; kc += 16) {
    float4 av = *(const float4*)(AT + (size_t)(kc + kr) * 4096 + mb * 64 + mc4);
    float4 wv = *(const float4*)(W + (size_t)(nb * 64 + lrow) * cH + kc + lcol);
    *(float4*)&As[kr][mc4] = av;
    Bs[lcol][lrow] = wv.x; Bs[lcol + 1][lrow] = wv.y; Bs[lcol + 2][lrow] = wv.z; Bs[lcol + 3][lrow] = wv.w;
    __syncthreads();
    #pragma unroll
    for (int kk = 0; kk < 16; ++kk) {
      float4 a4 = *(const float4*)&As[kk][tm * 4];
      float4 b4 = *(const float4*)&Bs[kk][tj * 4];
      acc[0][0] += a4.x * b4.x; acc[0][1] += a4.x * b4.y; acc[0][2] += a4.x * b4.z; acc[0][3] += a4.x * b4.w;
      acc[1][0] += a4.y * b4.x; acc[1][1] += a4.y * b4.y; acc[1][2] += a4.y * b4.z; acc[1][3] += a4.y * b4.w;
      acc[2][0] += a4.z * b4.x; acc[2][1] += a4.z * b4.y; acc[2][2] += a4.z * b4.z; acc[2][3] += a4.z * b4.w;
      acc[3][0] += a4.w * b4.x; acc[3][1] += a4.w * b4.y; acc[3][2] += a4.w * b4.z; acc[3][3] += a4.w * b4.w;
    }
    __syncthreads();
  }
  if (mode == 0) {
    #pragma unroll
    for (int j = 0; j < 4; ++j) {
      int o = nb * 64 + tj * 4 + j;
      float bv = bias[o];
      float4 o4;
      o4.x = fmaxf(acc[0][j] + bv, 0.f);
      o4.y = fmaxf(acc[1][j] + bv, 0.f);
      o4.z = fmaxf(acc[2][j] + bv, 0.f);
      o4.w = fmaxf(acc[3][j] + bv, 0.f);
      *(float4*)(C + (size_t)o * 4096 + mb * 64 + tm * 4) = o4;
    }
  } else {
    #pragma unroll
    for (int j = 0; j < 4; ++j) {
      int o = nb * 64 + tj * 4 + j;
      float bv = bias[o];
      float4 o4;
      o4.x = fmaxf(acc[0][j] + bv, 0.f);
      o4.y = fmaxf(acc[1][j] + bv, 0.f);
      o4.z = fmaxf(acc[2][j] + bv, 0.f);
      o4.w = fmaxf(acc[3][j] + bv, 0.f);
      *(float4*)(C + (size_t)mb * (64 * cH) + (size_t)o * 64 + tm * 4) = o4;
    }
  }
}

// ---------------------------------------------------------------------------
// lin split-K: part[kcb][n][o] = sum over K-chunk of x3t(64,16384)@lin_w(256,16384)^T
__global__ __launch_bounds__(256) void k_lin(const float* __restrict__ A,
                                             const float* __restrict__ W,
                                             float* __restrict__ part) {
  int nb = blockIdx.x, kcb = blockIdx.y, tid = threadIdx.x;
  int tm = tid & 15, tj = tid >> 4;
  __shared__ float As[16][68];
  __shared__ float Bs[16][68];
  float acc[4][4] = {{0.f}};
  int lrow = tid >> 2, lcol = (tid & 3) * 4;
  for (int kc = 0; kc < 256; kc += 16) {
    float4 av = *(const float4*)(A + (size_t)lrow * 16384 + kcb * 256 + kc + lcol);
    float4 wv = *(const float4*)(W + (size_t)(nb * 64 + lrow) * 16384 + kcb * 256 + kc + lcol);
    As[lcol][lrow] = av.x; As[lcol + 1][lrow] = av.y; As[lcol + 2][lrow] = av.z; As[lcol + 3][lrow] = av.w;
    Bs[lcol][lrow] = wv.x; Bs[lcol + 1][lrow] = wv.y; Bs[lcol + 2][lrow] = wv.z; Bs[lcol + 3][lrow] = wv.w;
    __syncthreads();
    #pragma unroll
    for (int kk = 0; kk < 16; ++kk) {
      float4 a4 = *(const float4*)&As[kk][tm * 4];
      float4 b4 = *(const float4*)&Bs[kk][tj * 4];
      acc[0][0] += a4.x * b4.x; acc[0][1] += a4.x * b4.y; acc[0][2] += a4.x * b4.z; acc[0][3] += a4.x * b4.w;
      acc[1][0] += a4.y * b4.x; acc[1][1] += a4.y * b4.y; acc[1][2] += a4.y * b4.z; acc[1][3] += a4.y * b4.w;
      acc[2][0] += a4.z * b4.x; acc[2][1] += a4.z * b4.y; acc[2][2] += a4.z * b4.z; acc[2][3] += a4.z * b4.w;
      acc[3][0] += a4.w * b4.x; acc[3][1] += a4.w * b4.y; acc[3][2] += a4.w * b4.z; acc[3][3] += a4.w * b4.w;
    }
    __syncthreads();
  }
  #pragma unroll
  for (int i = 0; i < 4; ++i) {
    int n = tm * 4 + i;
    float4 o4 = make_float4(acc[i][0], acc[i][1], acc[i][2], acc[i][3]);
    *(float4*)(part + ((size_t)kcb * cN + n) * cH + nb * 64 + tj * 4) = o4;
  }
}

// ---------------------------------------------------------------------------
// Tail per (t,n): reduce lin partials -> s; actor/probs; e=psi; cos; p_new; v;
// write row; then psb = softmax(p_new), r = psb @ M for t+1. (round-5 verbatim)
__global__ __launch_bounds__(256) void k_tail(const float* __restrict__ part,
                                              const float* __restrict__ lin_b,
                                              const float* __restrict__ actor_w,
                                              const float* __restrict__ actor_b,
                                              const float* __restrict__ critic_w,
                                              const float* __restrict__ critic_b,
                                              const float* __restrict__ psip,
                                              const float* __restrict__ psi_b,
                                              const float* __restrict__ inter,
                                              const int* __restrict__ actions,
                                              const float* __restrict__ X,
                                              const float* __restrict__ nMp,
                                              const float* __restrict__ nMm,
                                              float* __restrict__ psb,
                                              float* __restrict__ r,
                                              float* __restrict__ out, int t) {
  int n = blockIdx.x, tid = threadIdx.x;
  __shared__ float ss[cH];
  __shared__ float es[cH];
  __shared__ float lg[cAN], dp[cAN], nzv[cAN], prb[cAN];
  __shared__ float red[256];
  __shared__ float ared[16][17];
  __shared__ float cred[2][4][64];
  __shared__ float enorm_s;
  __shared__ float pns[cS];
  __shared__ float mx2, sm2;
  float* orow = out + ((size_t)t * cN + n) * cOW;
  float acc = lin_b[tid];
  for (int kc = 0; kc < 64; ++kc) acc += part[((size_t)kc * cN + n) * cH + tid];
  float sv = fmaxf(acc, 0.f);
  ss[tid] = sv;
  orow[1 + cAN + 1 + tid] = sv;
  __syncthreads();
  {
    int a = tid & 15, hg = tid >> 4;
    float pa = 0.f;
    const float* wr = actor_w + a * cH + hg * 16;
    const float* sh = &ss[hg * 16];
    #pragma unroll
    for (int hh2 = 0; hh2 < 16; ++hh2) pa += wr[hh2] * sh[hh2];
    ared[a][hg] = pa;
  }
  __syncthreads();
  if (tid < cAN) {
    float a = actor_b[tid];
    #pragma unroll
    for (int i = 0; i < 16; ++i) a += ared[tid][i];
    lg[tid] = a;
  }
  __syncthreads();
  if (tid < cAN) {
    float m = lg[0];
    for (int i = 1; i < cAN; ++i) m = fmaxf(m, lg[i]);
    dp[tid] = expf(lg[tid] - m);
  }
  __syncthreads();
  if (tid < cAN) {
    float s = 0.f;
    for (int i = 0; i < cAN; ++i) s += dp[i];
    float dprob = dp[tid] / s;
    float nv = (tid < 5) ? 1.f : inter[((size_t)t * cN + n) * (cAN - 5) + (tid - 5)];
    nzv[tid] = nv;
    prb[tid] = dprob * nv;
  }
  __syncthreads();
  if (tid < cAN) {
    float sp = 0.f, sn = 0.f;
    for (int i = 0; i < cAN; ++i) { sp += prb[i]; sn += nzv[i]; }
    float deficit = 1.f - sp;
    float v2 = prb[tid] + (nzv[tid] / fmaxf(sn, 1e-12f)) * deficit;
    prb[tid] = fminf(fmaxf(v2, 0.f), 1.f);
  }
  __syncthreads();
  if (tid < cAN) {
    float s = 0.f;
    for (int i = 0; i < cAN; ++i) s += prb[i];
    orow[1 + tid] = prb[tid] / fmaxf(s, 1e-12f);
  }
  int at = actions[t * cN + n];
  {
    float a = psi_b[tid];
    for (int h = 0; h < cH; ++h) a += psip[((size_t)at * cH + h) * cH + tid] * ss[h];
    es[tid] = a;
    red[tid] = a * a;
  }
  __syncthreads();
  for (int st = 128; st > 0; st >>= 1) {
    if (tid < st) red[tid] += red[tid + st];
    __syncthreads();
  }
  if (tid == 0) enorm_s = sqrtf(red[0]);
  __syncthreads();
  float enorm = enorm_s;
  red[tid] = critic_w[tid] * ss[tid];
  __syncthreads();
  for (int st = 128; st > 0; st >>= 1) {
    if (tid < st) red[tid] += red[tid + st];
    __syncthreads();
  }
  if (tid == 0) {
    orow[1 + cAN] = red[0] + critic_b[0];
    orow[0] = (float)at;
  }
  {
    int s2 = tid & 63, hg = tid >> 6;
    const float* xr = X + ((size_t)n * cS + s2) * XLD;
    const float* xp = xr + 2 + 2 * cH + hg * 64;
    const float* xm = xr + 2 + cH + hg * 64;
    const float* ep = &es[hg * 64];
    float dpp = 0.f, dmm = 0.f;
    #pragma unroll 8
    for (int h2 = 0; h2 < 64; ++h2) {
      float ev = ep[h2];
      dpp += ev * xp[h2];
      dmm += ev * xm[h2];
    }
    cred[0][hg][s2] = dpp;
    cred[1][hg][s2] = dmm;
  }
  __syncthreads();
  if (tid < cS) {
    float dpp = cred[0][0][tid] + cred[0][1][tid] + cred[0][2][tid] + cred[0][3][tid];
    float dmm = cred[1][0][tid] + cred[1][1][tid] + cred[1][2][tid] + cred[1][3][tid];
    const float* xr = X + ((size_t)n * cS + tid) * XLD;
    float cP = dpp / fmaxf(enorm * nMp[n * cS + tid], 1e-8f);
    float cM = dmm / fmaxf(enorm * nMm[n * cS + tid], 1e-8f);
    float cc = xr[0];
    float pn = psb[n * cS + tid] + cc * cP - cc * cM;
    pns[tid] = pn;
    orow[1 + cAN + 1 + cH + tid] = pn;
  }
  __threadfence_block();
  __syncthreads();
  if (t == cT - 1) {
    float* orow2 = out + (size_t)cT * cN * cOW + (size_t)n * cOW;
    orow2[tid] = orow[tid];
    if (tid + 256 < cOW) orow2[tid + 256] = orow[tid + 256];
  }
  if (tid == 0) { float m2 = pns[0]; for (int i = 1; i < cS; ++i) m2 = fmaxf(m2, pns[i]); mx2 = m2; }
  __syncthreads();
  if (tid < cS) pns[tid] = expf(pns[tid] - mx2);
  __syncthreads();
  if (tid == 0) { float s2 = 0.f; for (int i = 0; i < cS; ++i) s2 += pns[i]; sm2 = s2; }
  __syncthreads();
  if (tid < cS) { pns[tid] /= sm2; psb[n * cS + tid] = pns[tid]; }
  __syncthreads();
  float acc2 = 0.f;
  for (int s2 = 0; s2 < cS; ++s2)
    acc2 += pns[s2] * X[((size_t)n * cS + s2) * XLD + 2 + tid];
  r[n * cH + tid] = acc2;
}

// ---------------------------------------------------------------------------
extern "C" void kernel_launch(void* const* d_in, const int* in_sizes, int n_in,
                              void* d_out, int out_size, void* d_ws, size_t ws_size,
                              hipStream_t stream) {
  const float* base     = (const float*)d_in[0];
  const float* inter    = (const float*)d_in[1];
  const float* hxs      = (const float*)d_in[2];
  const float* emb      = (const float*)d_in[3];
  const float* w_ih     = (const float*)d_in[4];
  const float* w_hh     = (const float*)d_in[5];
  const float* b_ih     = (const float*)d_in[6];
  const float* b_hh     = (const float*)d_in[7];
  const float* conv0_w  = (const float*)d_in[8];
  const float* conv0_b  = (const float*)d_in[9];
  const float* convs_w  = (const float*)d_in[10];
  const float* convs_b  = (const float*)d_in[11];
  const float* lin_w    = (const float*)d_in[12];
  const float* lin_b    = (const float*)d_in[13];
  const float* psi_w    = (const float*)d_in[14];
  const float* psi_b    = (const float*)d_in[15];
  const float* actor_w  = (const float*)d_in[16];
  const float* actor_b  = (const float*)d_in[17];
  const float* critic_w = (const float*)d_in[18];
  const float* critic_b = (const float*)d_in[19];
  const int*   subtasks = (const int*)d_in[20];
  const int*   actions  = (const int*)d_in[21];
  float* out = (float*)d_out;
  float* ws  = (float*)d_ws;

  // ws layout (floats): round-5 layout + w0r (131,072) at the end.
  float* gitp   = ws + 0;          // 79,872  [GRU]
  float* psb    = ws + 0;          // 4,096   (post-GRU)
  float* r      = ws + 4096;       // 16,384
  float* nMp    = ws + 20480;      // 4,096
  float* nMm    = ws + 24576;      // 4,096
  float* X      = ws + 79872;      // 3,276,800 (persists)
  float* wpadG  = ws + 3356672;    // 2,048,000 [GRU]
  float* psip   = ws + 3356672;    // 1,048,576 (post-GRU)
  float* x1T    = ws + 4405248;    // 1,048,576 (lin partials only now)
  float* part   = x1T;
  float* partG  = ws + 5404672;    // 655,360 [GRU]
  float* x2T    = ws + 5453824;    // 1,048,576 [t-loop] (overlaps partG: GRU-only)
  float* x3t    = ws + 6502400;    // 1,048,576 [t-loop]
  float* w0r    = ws + 7550976;    // 131,072 -> end 7,682,048 (~30.7 MB)

  k_gitab<<<dim3(10, 32), 256, 0, stream>>>(emb, w_ih, b_ih, gitp);
  k_wpad<<<8000, 256, 0, stream>>>(w_hh, wpadG);
  k_gru_gate<<<dim3(4, 64), 256, 0, stream>>>(partG, b_hh, gitp, subtasks, X, 0);
  for (int s = 1; s < cS; ++s) {
    k_gru_gemm<<<160, 256, 0, stream>>>(wpadG, X, partG, s);
    k_gru_gate<<<dim3(4, 64), 256, 0, stream>>>(partG, b_hh, gitp, subtasks, X, s);
  }
  k_psiperm<<<4096, 256, 0, stream>>>(psi_w, psip);  // after GRU (psip aliases wpadG)
  k_pinit<<<64, 256, 0, stream>>>(hxs, X, psb, r, nMp, nMm);
  for (int t = 0; t < cT; ++t) {
    k_front0<<<256, 256, 0, stream>>>(r, conv0_w, w0r);
    k_conv1f<<<256, 256, 0, stream>>>(w0r, base, conv0_b, convs_w, convs_b, x2T, t);
    k_gemmT<<<dim3(4, 64), 256, 0, stream>>>(x2T, convs_w + 65536, convs_b + 256, x3t, 1);
    k_lin<<<dim3(4, 64), 256, 0, stream>>>(x3t, lin_w, part);
    k_tail<<<64, 256, 0, stream>>>(part, lin_b, actor_w, actor_b, critic_w, critic_b,
                                   psip, psi_b, inter, actions, X, nMp, nMm,
                                   psb, r, out, t);
  }
}